// Round 2
// baseline (713.201 us; speedup 1.0000x reference)
//
#include <hip/hip_runtime.h>
#include <math.h>

#define BB 4
#define SS 2048
#define NN 4096
#define DD 256
#define ROWS (BB*SS)        // 8192
#define TOPN 5
#define NCB (NN/64)         // 64 column blocks
#define PVSTRIDE (NCB*TOPN) // 320
#define NCAND 16

// ---------------- K1: qp = q @ Wq^T + bq, fp64 accumulate ----------------
// TM=64 rows, TN=64 outs, KB=64, 256 threads, stride-65 LDS (conflict-free)
__global__ __launch_bounds__(256) void k_proj64(
    const float* __restrict__ q, const float* __restrict__ Wq,
    const float* __restrict__ bq, double* __restrict__ qp64,
    float* __restrict__ qp32)
{
    __shared__ float As[64][65];
    __shared__ float Bs[64][65];
    const int rowbase = blockIdx.x * 64;
    const int ebase   = blockIdx.y * 64;
    const int t  = threadIdx.x;
    const int tx = t & 15;
    const int ty = t >> 4;

    double acc[4][4];
    #pragma unroll
    for (int i = 0; i < 4; ++i)
        #pragma unroll
        for (int j = 0; j < 4; ++j) acc[i][j] = 0.0;

    for (int k0 = 0; k0 < DD; k0 += 64) {
        #pragma unroll
        for (int i = 0; i < 4; ++i) {
            int r = ty + (i << 4);
            float4 va = *(const float4*)(q  + (size_t)(rowbase + r) * DD + k0 + (tx << 2));
            As[(tx<<2)+0][r] = va.x; As[(tx<<2)+1][r] = va.y;
            As[(tx<<2)+2][r] = va.z; As[(tx<<2)+3][r] = va.w;
            float4 vb = *(const float4*)(Wq + (size_t)(ebase + r) * DD + k0 + (tx << 2));
            Bs[(tx<<2)+0][r] = vb.x; Bs[(tx<<2)+1][r] = vb.y;
            Bs[(tx<<2)+2][r] = vb.z; Bs[(tx<<2)+3][r] = vb.w;
        }
        __syncthreads();
        #pragma unroll 4
        for (int kk = 0; kk < 64; ++kk) {
            double a[4], bb[4];
            #pragma unroll
            for (int i = 0; i < 4; ++i) a[i]  = (double)As[kk][(ty<<2)+i];
            #pragma unroll
            for (int j = 0; j < 4; ++j) bb[j] = (double)Bs[kk][(tx<<2)+j];
            #pragma unroll
            for (int i = 0; i < 4; ++i)
                #pragma unroll
                for (int j = 0; j < 4; ++j)
                    acc[i][j] = fma(a[i], bb[j], acc[i][j]);
        }
        __syncthreads();
    }
    #pragma unroll
    for (int i = 0; i < 4; ++i) {
        int row = rowbase + (ty << 2) + i;
        #pragma unroll
        for (int j = 0; j < 4; ++j) {
            int e = ebase + (tx << 2) + j;
            double r = acc[i][j] + (double)bq[e];
            qp64[(size_t)row * DD + e] = r;
            qp32[(size_t)row * DD + e] = (float)r;
        }
    }
}

// ------------- rownorm (double input): sum(x^2) in fp64, 1 wave/row -------
__global__ __launch_bounds__(256) void k_rownorm_d(
    const double* __restrict__ x, double* __restrict__ o64,
    float* __restrict__ o32)
{
    int row  = blockIdx.x * 4 + (threadIdx.x >> 6);
    int lane = threadIdx.x & 63;
    const double* p = x + (size_t)row * DD + (lane << 2);
    double s = p[0]*p[0] + p[1]*p[1] + p[2]*p[2] + p[3]*p[3];
    #pragma unroll
    for (int off = 32; off; off >>= 1) s += __shfl_xor(s, off);
    if (lane == 0) { o64[row] = s; o32[row] = (float)s; }
}

// ------------- rownorm (float input): sum(x^2) in fp64, 1 wave/row --------
__global__ __launch_bounds__(256) void k_rownorm_f(
    const float* __restrict__ x, double* __restrict__ o64,
    float* __restrict__ o32)
{
    int row  = blockIdx.x * 4 + (threadIdx.x >> 6);
    int lane = threadIdx.x & 63;
    float4 v = *(const float4*)(x + (size_t)row * DD + (lane << 2));
    double s = (double)v.x*(double)v.x + (double)v.y*(double)v.y
             + (double)v.z*(double)v.z + (double)v.w*(double)v.w;
    #pragma unroll
    for (int off = 32; off; off >>= 1) s += __shfl_xor(s, off);
    if (lane == 0) { o64[row] = s; o32[row] = (float)s; }
}

// ------------- gate: sigmoid(q . wg + bg) in fp64, 1 wave/row -------------
__global__ __launch_bounds__(256) void k_gate(
    const float* __restrict__ q, const float* __restrict__ wg,
    const float* __restrict__ bg, double* __restrict__ g64,
    float* __restrict__ g32)
{
    int row  = blockIdx.x * 4 + (threadIdx.x >> 6);
    int lane = threadIdx.x & 63;
    float4 v = *(const float4*)(q  + (size_t)row * DD + (lane << 2));
    float4 w = *(const float4*)(wg + (lane << 2));
    double s = (double)v.x*(double)w.x + (double)v.y*(double)w.y
             + (double)v.z*(double)w.z + (double)v.w*(double)w.w;
    #pragma unroll
    for (int off = 32; off; off >>= 1) s += __shfl_xor(s, off);
    if (lane == 0) {
        double g = 1.0 / (1.0 + exp(-(s + (double)bg[0])));
        g64[row] = g; g32[row] = (float)g;
    }
}

// ---------------- K3: fused distance GEMM (fp32 filter) + block top-5 -----
__global__ __launch_bounds__(256) void k_dist(
    const float* __restrict__ qp, const float* __restrict__ ctx,
    const float* __restrict__ mem, const float* __restrict__ q2,
    const float* __restrict__ gate, const float* __restrict__ c2c,
    const float* __restrict__ c2m, float* __restrict__ pvals,
    int* __restrict__ pidx)
{
    __shared__ float As[64][65];
    __shared__ float Bc[64][65];
    __shared__ float Bm[64][65];
    const int rowbase = blockIdx.x * 64;
    const int colbase = blockIdx.y * 64;
    const int b = rowbase / SS;
    const float* cbp = ctx + (size_t)b * NN * DD;
    const float* mbp = mem + (size_t)b * NN * DD;
    const int t  = threadIdx.x;
    const int tx = t & 15;
    const int ty = t >> 4;

    float accC[4][4], accM[4][4];
    #pragma unroll
    for (int i = 0; i < 4; ++i)
        #pragma unroll
        for (int j = 0; j < 4; ++j) { accC[i][j] = 0.0f; accM[i][j] = 0.0f; }

    for (int k0 = 0; k0 < DD; k0 += 64) {
        #pragma unroll
        for (int i = 0; i < 4; ++i) {
            int r = ty + (i << 4);
            float4 va = *(const float4*)(qp  + (size_t)(rowbase + r) * DD + k0 + (tx << 2));
            As[(tx<<2)+0][r] = va.x; As[(tx<<2)+1][r] = va.y;
            As[(tx<<2)+2][r] = va.z; As[(tx<<2)+3][r] = va.w;
            float4 vc = *(const float4*)(cbp + (size_t)(colbase + r) * DD + k0 + (tx << 2));
            Bc[(tx<<2)+0][r] = vc.x; Bc[(tx<<2)+1][r] = vc.y;
            Bc[(tx<<2)+2][r] = vc.z; Bc[(tx<<2)+3][r] = vc.w;
            float4 vm = *(const float4*)(mbp + (size_t)(colbase + r) * DD + k0 + (tx << 2));
            Bm[(tx<<2)+0][r] = vm.x; Bm[(tx<<2)+1][r] = vm.y;
            Bm[(tx<<2)+2][r] = vm.z; Bm[(tx<<2)+3][r] = vm.w;
        }
        __syncthreads();
        #pragma unroll 4
        for (int kk = 0; kk < 64; ++kk) {
            float a[4], bcv[4], bmv[4];
            #pragma unroll
            for (int i = 0; i < 4; ++i) a[i]   = As[kk][(ty<<2)+i];
            #pragma unroll
            for (int j = 0; j < 4; ++j) bcv[j] = Bc[kk][(tx<<2)+j];
            #pragma unroll
            for (int j = 0; j < 4; ++j) bmv[j] = Bm[kk][(tx<<2)+j];
            #pragma unroll
            for (int i = 0; i < 4; ++i)
                #pragma unroll
                for (int j = 0; j < 4; ++j) {
                    accC[i][j] = fmaf(a[i], bcv[j], accC[i][j]);
                    accM[i][j] = fmaf(a[i], bmv[j], accM[i][j]);
                }
        }
        __syncthreads();
    }

    float q2r[4], gr[4];
    #pragma unroll
    for (int i = 0; i < 4; ++i) {
        int row = rowbase + (ty << 2) + i;
        q2r[i] = q2[row];
        gr[i]  = gate[row];
    }
    float cc[4], cm[4];
    #pragma unroll
    for (int j = 0; j < 4; ++j) {
        int col = colbase + (tx << 2) + j;
        cc[j] = c2c[b * NN + col];
        cm[j] = c2m[b * NN + col];
    }
    #pragma unroll
    for (int i = 0; i < 4; ++i)
        #pragma unroll
        for (int j = 0; j < 4; ++j) {
            float dc = sqrtf(fmaxf(q2r[i] + cc[j] - 2.0f * accC[i][j], 0.0f));
            float dm = sqrtf(fmaxf(q2r[i] + cm[j] - 2.0f * accM[i][j], 0.0f));
            As[(ty<<2)+i][(tx<<2)+j] = gr[i] * dc + (1.0f - gr[i]) * dm;
        }
    __syncthreads();

    if (t < 64) {
        float b0 = INFINITY, b1 = INFINITY, b2 = INFINITY, b3 = INFINITY, b4 = INFINITY;
        int   i0 = 0x7fffffff, i1 = 0x7fffffff, i2 = 0x7fffffff, i3 = 0x7fffffff, i4 = 0x7fffffff;
        for (int c = 0; c < 64; ++c) {
            float v = As[t][c];
            if (v < b4) {
                int gi = colbase + c;
                if (v < b3) {
                    b4 = b3; i4 = i3;
                    if (v < b2) {
                        b3 = b2; i3 = i2;
                        if (v < b1) {
                            b2 = b1; i2 = i1;
                            if (v < b0) { b1 = b0; i1 = i0; b0 = v; i0 = gi; }
                            else        { b1 = v;  i1 = gi; }
                        } else { b2 = v; i2 = gi; }
                    } else { b3 = v; i3 = gi; }
                } else { b4 = v; i4 = gi; }
            }
        }
        size_t base = (size_t)(rowbase + t) * PVSTRIDE + (size_t)blockIdx.y * TOPN;
        pvals[base+0] = b0; pvals[base+1] = b1; pvals[base+2] = b2;
        pvals[base+3] = b3; pvals[base+4] = b4;
        pidx[base+0] = i0; pidx[base+1] = i1; pidx[base+2] = i2;
        pidx[base+3] = i3; pidx[base+4] = i4;
    }
}

// ---------------- K4: merge 320 partials -> top-16 candidate indices ------
__global__ __launch_bounds__(256) void k_merge16(
    const float* __restrict__ pvals, const int* __restrict__ pidx,
    int* __restrict__ cand)
{
    int row  = blockIdx.x * 4 + (threadIdx.x >> 6);
    int lane = threadIdx.x & 63;
    size_t base = (size_t)row * PVSTRIDE + (size_t)lane * TOPN;
    float h0 = pvals[base+0], h1 = pvals[base+1], h2 = pvals[base+2],
          h3 = pvals[base+3], h4 = pvals[base+4];
    int   j0 = pidx[base+0], j1 = pidx[base+1], j2 = pidx[base+2],
          j3 = pidx[base+3], j4 = pidx[base+4];

    #pragma unroll
    for (int r = 0; r < NCAND; ++r) {
        float mv = h0; int mi = j0;
        #pragma unroll
        for (int off = 1; off < 64; off <<= 1) {
            float ov = __shfl_xor(mv, off);
            int   oi = __shfl_xor(mi, off);
            if (ov < mv || (ov == mv && oi < mi)) { mv = ov; mi = oi; }
        }
        if (h0 == mv && j0 == mi) {
            h0 = h1; j0 = j1; h1 = h2; j1 = j2; h2 = h3; j2 = j3;
            h3 = h4; j3 = j4; h4 = INFINITY; j4 = 0x7fffffff;
        }
        if (lane == 0) cand[(size_t)row * NCAND + r] = mi;
    }
}

// ---------------- K5: fp64 exact rescore of 16 candidates, final top-5 ----
__global__ __launch_bounds__(64) void k_rescore(
    const double* __restrict__ qp64, const float* __restrict__ ctx,
    const float* __restrict__ mem, const double* __restrict__ q2,
    const double* __restrict__ gate, const double* __restrict__ c2c,
    const double* __restrict__ c2m, const int* __restrict__ cand,
    float* __restrict__ out)
{
    __shared__ double sval[NCAND];
    __shared__ int    sidx[NCAND];
    const int row  = blockIdx.x;
    const int lane = threadIdx.x;
    const int b = row / SS;

    const double* qr = qp64 + (size_t)row * DD + (lane << 2);
    double a0 = qr[0], a1 = qr[1], a2 = qr[2], a3 = qr[3];
    double q2r = q2[row], g = gate[row];

    for (int c = 0; c < NCAND; ++c) {
        int idx = cand[(size_t)row * NCAND + c];
        const float4 vc = *(const float4*)(ctx + ((size_t)b * NN + idx) * DD + (lane << 2));
        const float4 vm = *(const float4*)(mem + ((size_t)b * NN + idx) * DD + (lane << 2));
        double sc = a0*(double)vc.x + a1*(double)vc.y + a2*(double)vc.z + a3*(double)vc.w;
        double sm = a0*(double)vm.x + a1*(double)vm.y + a2*(double)vm.z + a3*(double)vm.w;
        #pragma unroll
        for (int off = 32; off; off >>= 1) {
            sc += __shfl_xor(sc, off);
            sm += __shfl_xor(sm, off);
        }
        if (lane == 0) {
            double dc = sqrt(fmax(q2r + c2c[(size_t)b * NN + idx] - 2.0 * sc, 0.0));
            double dm = sqrt(fmax(q2r + c2m[(size_t)b * NN + idx] - 2.0 * sm, 0.0));
            sval[c] = g * dc + (1.0 - g) * dm;
            sidx[c] = idx;
        }
    }
    __syncthreads();
    if (lane == 0) {
        #pragma unroll
        for (int r = 0; r < TOPN; ++r) {
            double bv = sval[0]; int bi = sidx[0]; int bp = 0;
            for (int c = 1; c < NCAND; ++c) {
                double v = sval[c]; int ii = sidx[c];
                if (v < bv || (v == bv && ii < bi)) { bv = v; bi = ii; bp = c; }
            }
            sval[bp] = INFINITY; sidx[bp] = 0x7fffffff;
            out[(size_t)row * TOPN + r] = (float)bv;
            out[(size_t)ROWS * TOPN + (size_t)row * TOPN + r] = (float)bi;
        }
    }
}

extern "C" void kernel_launch(void* const* d_in, const int* in_sizes, int n_in,
                              void* d_out, int out_size, void* d_ws, size_t ws_size,
                              hipStream_t stream)
{
    const float* q   = (const float*)d_in[0];
    const float* ctx = (const float*)d_in[1];
    const float* mem = (const float*)d_in[2];
    const float* Wq  = (const float*)d_in[3];
    const float* bq  = (const float*)d_in[4];
    const float* wg  = (const float*)d_in[5];
    const float* bg  = (const float*)d_in[6];
    float* out = (float*)d_out;

    // workspace layout: doubles first (alignment), then floats, then ints
    char* ws = (char*)d_ws;
    double* qp64  = (double*)ws;                 ws += (size_t)ROWS * DD * 8;   // 16 MB
    double* q264  = (double*)ws;                 ws += (size_t)ROWS * 8;
    double* g64   = (double*)ws;                 ws += (size_t)ROWS * 8;
    double* c2c64 = (double*)ws;                 ws += (size_t)BB * NN * 8;
    double* c2m64 = (double*)ws;                 ws += (size_t)BB * NN * 8;
    float*  qp32  = (float*)ws;                  ws += (size_t)ROWS * DD * 4;   // 8 MB
    float*  q232  = (float*)ws;                  ws += (size_t)ROWS * 4;
    float*  g32   = (float*)ws;                  ws += (size_t)ROWS * 4;
    float*  c2c32 = (float*)ws;                  ws += (size_t)BB * NN * 4;
    float*  c2m32 = (float*)ws;                  ws += (size_t)BB * NN * 4;
    float*  pvals = (float*)ws;                  ws += (size_t)ROWS * PVSTRIDE * 4; // 10.5 MB
    int*    pidx  = (int*)ws;                    ws += (size_t)ROWS * PVSTRIDE * 4; // 10.5 MB
    int*    cand  = (int*)ws;                    ws += (size_t)ROWS * NCAND * 4;

    k_proj64<<<dim3(ROWS/64, DD/64), 256, 0, stream>>>(q, Wq, bq, qp64, qp32);
    k_rownorm_d<<<ROWS/4, 256, 0, stream>>>(qp64, q264, q232);
    k_rownorm_f<<<(BB*NN)/4, 256, 0, stream>>>(ctx, c2c64, c2c32);
    k_rownorm_f<<<(BB*NN)/4, 256, 0, stream>>>(mem, c2m64, c2m32);
    k_gate<<<ROWS/4, 256, 0, stream>>>(q, wg, bg, g64, g32);
    k_dist<<<dim3(ROWS/64, NN/64), 256, 0, stream>>>(qp32, ctx, mem, q232, g32,
                                                     c2c32, c2m32, pvals, pidx);
    k_merge16<<<ROWS/4, 256, 0, stream>>>(pvals, pidx, cand);
    k_rescore<<<ROWS, 64, 0, stream>>>(qp64, ctx, mem, q264, g64,
                                       c2c64, c2m64, cand, out);
}